// Round 4
// baseline (336.835 us; speedup 1.0000x reference)
//
#include <hip/hip_runtime.h>

typedef _Float16 f16x8 __attribute__((ext_vector_type(8)));
typedef _Float16 f16x4 __attribute__((ext_vector_type(4)));
typedef float f32x4 __attribute__((ext_vector_type(4)));

#define T_DIM 2048
#define E_DIM 2048
#define D_DIM 128
#define NB 4
#define KSP_P 8    // proj K-splits (K=2048 -> 256 each)
#define KCH_P 256
#define KSP_A 8    // av K-splits (chunks of 256 over s)
#define KCH_A 256
#define NCH2 32    // stats chunks of 64 t-rows

__device__ __forceinline__ void gll16(const void* g, void* l) {
  __builtin_amdgcn_global_load_lds(
      (const __attribute__((address_space(1))) unsigned int*)g,
      (__attribute__((address_space(3))) unsigned int*)l, 16, 0, 0);
}

__device__ __forceinline__ void merge_stat(float& m, float& l, float pm, float pl) {
  if (pm != -__builtin_inff()) {
    float nm = fmaxf(m, pm);
    l = l * __expf(m - nm) + pl * __expf(pm - nm);
    m = nm;
  }
}

// ---------------- prep: W [E,D] fp32 -> WhT [D,E] fp16 (3 mats) + zero Z ----------------

__global__ void prep(const float* __restrict__ Wq, const float* __restrict__ Wk,
                     const float* __restrict__ Wv, _Float16* __restrict__ WhT,
                     float* __restrict__ Z) {
  int idx = blockIdx.x * 256 + threadIdx.x;  // 0..262143
  int y = blockIdx.y;
  if (y < 3) {
    const float* W = (y == 0) ? Wq : ((y == 1) ? Wk : Wv);
    int e = idx & (E_DIM - 1), d = idx >> 11;
    WhT[(size_t)y * (D_DIM * E_DIM) + idx] = (_Float16)W[e * D_DIM + d];
  } else {
    // zero Z: 4*2048*128 f32 = 4 MB = 262144 * 16 B
    f32x4 z = {0.f, 0.f, 0.f, 0.f};
    *(f32x4*)(Z + (size_t)idx * 4) = z;
  }
}

// ---------------- projection GEMM: fused QKV, 64x384 tile, split-K x8, BK=32 ----------------
// TLP structure (r0-proven loop, reverting r1-r3 micro-scheduling): 1024 blocks
// (grid 128x8), 384 thr (6 waves), 32 KB single-buffered LDS, VGPR<=85 via
// launch_bounds -> 4 blocks/CU resident = 24 waves/CU. Latency of the per-step
// barrier drain is hidden by the other 3 blocks' compute (m114 implicit overlap);
// no inline waitcnt/setprio - compiler-scheduled.
// A (x fp32) staged via gll16, seg^(row&7) swizzle, cvt fp32->fp16 at fragment
// read (VALU is idle). B (WhT fp16) staged via gll16, seg^((row>>1)&3) swizzle.
// Partials fp16 into Ph[slot<<20], slot = ks*3+mat; V stored pre-transposed.

__global__ __launch_bounds__(384, 6) void proj_gemm(
    const float* __restrict__ x, const _Float16* __restrict__ WhT,
    _Float16* __restrict__ Ph) {
  __shared__ float Asw[64 * 32];      // 8 KB fp32, swizzled
  __shared__ _Float16 Bsw[384 * 32];  // 24 KB fp16, swizzled (Q|K|V rows)
  const int tid = threadIdx.x, w = tid >> 6, lane = tid & 63;
  const int wn = w, quad = lane >> 4, l16 = lane & 15;
  const int t0 = blockIdx.x * 64;
  const int ks = blockIdx.y;
  const int kb = ks * KCH_P;
  // A staging: items 0..511 (row = i>>3, seg = i&7); thread does item tid,
  // threads 0..127 also item 384+tid (384 % 8 == 0 so seg = tid&7 both times).
  const int ar0 = tid >> 3, aseg = tid & 7;
  const int ar1 = (384 + tid) >> 3;
  // B staging: items 0..1535 (row = i>>2, seg = i&3), 4 per thread (i = tid+384p).
  const int br = tid >> 2, bseg = tid & 3;

  f32x4 acc[4][4] = {};
  for (int k0 = kb; k0 < kb + KCH_P; k0 += 32) {
    __syncthreads();
    {
      int g = aseg ^ (ar0 & 7);
      gll16(x + (size_t)(t0 + ar0) * E_DIM + k0 + g * 4, Asw + tid * 4);
      if (tid < 128) {
        int g2 = aseg ^ (ar1 & 7);
        gll16(x + (size_t)(t0 + ar1) * E_DIM + k0 + g2 * 4, Asw + (384 + tid) * 4);
      }
    }
#pragma unroll
    for (int p = 0; p < 4; ++p) {
      int r = p * 96 + br;
      int g = bseg ^ ((r >> 1) & 3);
      gll16(WhT + (size_t)r * E_DIM + k0 + g * 8, Bsw + (p * 384 + tid) * 8);
    }
    __syncthreads();
    f16x8 af[4], bf[4];
#pragma unroll
    for (int i = 0; i < 4; ++i) {
      int row = i * 16 + l16;
      int s0 = (2 * quad) ^ (row & 7);
      int s1 = (2 * quad + 1) ^ (row & 7);
      f32x4 a0 = *(const f32x4*)(Asw + row * 32 + s0 * 4);
      f32x4 a1 = *(const f32x4*)(Asw + row * 32 + s1 * 4);
#pragma unroll
      for (int e = 0; e < 4; ++e) {
        af[i][e] = (_Float16)a0[e];
        af[i][e + 4] = (_Float16)a1[e];
      }
    }
#pragma unroll
    for (int j = 0; j < 4; ++j) {
      int row = wn * 64 + j * 16 + l16;
      int sg = (quad ^ ((row >> 1) & 3)) * 8;
      bf[j] = *(const f16x8*)(Bsw + row * 32 + sg);
    }
#pragma unroll
    for (int i = 0; i < 4; ++i)
#pragma unroll
      for (int j = 0; j < 4; ++j)
        acc[i][j] = __builtin_amdgcn_mfma_f32_16x16x32_f16(af[i], bf[j], acc[i][j], 0, 0, 0);
  }
  const int mat = wn >> 1;
  const int nb0 = (wn & 1) * 64;
  _Float16* P = Ph + ((size_t)(ks * 3 + mat) << 20);
  if (mat < 2) {
#pragma unroll
    for (int i = 0; i < 4; ++i)
#pragma unroll
      for (int j = 0; j < 4; ++j) {
        int n = nb0 + j * 16 + l16;
#pragma unroll
        for (int r = 0; r < 4; ++r) {
          int t = t0 + i * 16 + quad * 4 + r;
          P[(size_t)t * D_DIM + n] = (_Float16)acc[i][j][r];
        }
      }
  } else {
    // V: pre-transposed partial, 4 consecutive t at fixed n -> f16x4 store
#pragma unroll
    for (int i = 0; i < 4; ++i)
#pragma unroll
      for (int j = 0; j < 4; ++j) {
        int n = nb0 + j * 16 + l16;
        int t = t0 + i * 16 + quad * 4;
        f16x4 o;
#pragma unroll
        for (int r = 0; r < 4; ++r) o[r] = (_Float16)acc[i][j][r];
        *(f16x4*)(P + ((size_t)(t >> 11) * D_DIM + n) * T_DIM + (t & (T_DIM - 1))) = o;
      }
  }
}

// ---------------- reduce proj partials (8 slots) -> Qh, Kh, VT ----------------

__global__ void proj_reduce(const _Float16* __restrict__ Ph, _Float16* __restrict__ Qh,
                            _Float16* __restrict__ Kh, _Float16* __restrict__ VT) {
  size_t u = ((size_t)blockIdx.x * 256 + threadIdx.x) * 8;
  int mat = (int)(u >> 20);
  size_t rem = u & ((1u << 20) - 1);
  float s[8] = {};
#pragma unroll
  for (int ks = 0; ks < KSP_P; ++ks) {
    f16x8 p = *(const f16x8*)(Ph + ((size_t)(ks * 3 + mat) << 20) + rem);
#pragma unroll
    for (int e = 0; e < 8; ++e) s[e] += (float)p[e];
  }
  f16x8 o;
#pragma unroll
  for (int e = 0; e < 8; ++e) o[e] = (_Float16)s[e];
  _Float16* dst = (mat == 0) ? Qh : ((mat == 1) ? Kh : VT);
  *(f16x8*)(dst + rem) = o;
}

// ---------------- S = Q K^T / sqrt(D), single-barrier full-K + fused stats ----------------
// grid (136, 4): triangular (t,s) tile pair, y = batch. B staged once (4 BK=32
// sub-tiles, swizzled); A direct global->VGPR; 64 MFMA straight; stats epilogue
// single-pass: masked/scaled values cached in regs.

__global__ __launch_bounds__(256) void s_gemm(const _Float16* __restrict__ Qh,
                                              const _Float16* __restrict__ Kh,
                                              _Float16* __restrict__ S,
                                              float* __restrict__ Pm,
                                              float* __restrict__ Pl) {
  // triangular decode
  int idx = blockIdx.x;
  int xt = (int)((sqrtf(8.f * idx + 1.f) - 1.f) * 0.5f);
  while ((xt + 1) * (xt + 2) / 2 <= idx) ++xt;
  while (xt * (xt + 1) / 2 > idx) --xt;
  int yt = idx - xt * (xt + 1) / 2;
  __shared__ _Float16 Bs[4][128 * 32];
  const int tid = threadIdx.x, w = tid >> 6, lane = tid & 63;
  const int wr = w >> 1, wc = w & 1, quad = lane >> 4, l16 = lane & 15;
  const int t0 = xt * 128, s0 = yt * 128, b = blockIdx.y;
  const _Float16* A = Qh + (size_t)b * T_DIM * D_DIM;
  const _Float16* B = Kh + (size_t)b * T_DIM * D_DIM;
  const int srow = lane >> 2;
  const int swz = ((lane & 3) ^ ((srow >> 1) & 3)) * 8;  // source-col swizzle
#pragma unroll
  for (int kq = 0; kq < 4; ++kq)
#pragma unroll
    for (int q = 0; q < 2; ++q) {
      int rbase = w * 32 + q * 16;
      gll16(B + (size_t)(s0 + rbase + srow) * D_DIM + kq * 32 + swz,
            Bs[kq] + rbase * 32);
    }
  __syncthreads();
  f32x4 acc[4][4] = {};
  const int bsg = (quad ^ ((l16 >> 1) & 3)) * 8;
#pragma unroll
  for (int kq = 0; kq < 4; ++kq) {
    f16x8 af[4], bf[4];
#pragma unroll
    for (int i = 0; i < 4; ++i)
      af[i] = *(const f16x8*)(A + (size_t)(t0 + wr * 64 + i * 16 + l16) * D_DIM +
                              kq * 32 + quad * 8);
#pragma unroll
    for (int j = 0; j < 4; ++j)
      bf[j] = *(const f16x8*)(Bs[kq] + (wc * 64 + j * 16 + l16) * 32 + bsg);
#pragma unroll
    for (int i = 0; i < 4; ++i)
#pragma unroll
      for (int j = 0; j < 4; ++j)
        acc[i][j] = __builtin_amdgcn_mfma_f32_16x16x32_f16(af[i], bf[j], acc[i][j], 0, 0, 0);
  }
  _Float16* Sb = S + (size_t)b * T_DIM * T_DIM;
  const float scale = 0.08838834764831845f;  // 1/sqrt(128)
  const float NEG = -__builtin_inff();
#pragma unroll
  for (int j = 0; j < 4; ++j) {
    const int s = s0 + wc * 64 + j * 16 + l16;
    float vv[16];
    float m = NEG;
#pragma unroll
    for (int i = 0; i < 4; ++i)
#pragma unroll
      for (int r = 0; r < 4; ++r) {
        int t = t0 + wr * 64 + i * 16 + quad * 4 + r;
        float v = (s > t) ? NEG : acc[i][j][r] * scale;
        Sb[(size_t)t * T_DIM + s] = (_Float16)v;
        vv[i * 4 + r] = v;
        m = fmaxf(m, v);
      }
    float l = 0.f;
    if (m != NEG) {
#pragma unroll
      for (int k = 0; k < 16; ++k) l += __expf(vv[k] - m);  // exp(-inf - m) = 0
    }
    // merge across quad dim (lanes xor 16, 32)
#pragma unroll
    for (int d = 16; d <= 32; d <<= 1) {
      float pm = __shfl_xor(m, d, 64);
      float pl = __shfl_xor(l, d, 64);
      merge_stat(m, l, pm, pl);
    }
    if (quad == 0) {
      int c = 2 * xt + wr;
      Pm[((size_t)c * NB + b) * T_DIM + s] = m;
      Pl[((size_t)c * NB + b) * T_DIM + s] = l;
    }
  }
}

// ---------------- Z = A V, split-K: grid (16, 4, KSP_A), atomic accumulate ----------------
// Inline column stats (replaces comb_stats kernel); As/Bs swizzled; double-
// buffered one-barrier loop; epilogue atomicAdd into pre-zeroed Z.

__global__ __launch_bounds__(256) void av_gemm(const _Float16* __restrict__ S,
                                               const _Float16* __restrict__ VT,
                                               const float* __restrict__ Pm,
                                               const float* __restrict__ Pl,
                                               float* __restrict__ Z) {
  const int t0 = blockIdx.x * 128, b = blockIdx.y, ks = blockIdx.z;
  const int Kmax = t0 + 128;
  const int Kstart = ks * KCH_A;
  if (Kstart >= Kmax) return;
  const int Kend = (Kstart + KCH_A < Kmax) ? (Kstart + KCH_A) : Kmax;
  const int nit = (Kend - Kstart) >> 5;  // 4 or 8
  __shared__ _Float16 As[2][128 * 32];
  __shared__ _Float16 Bs[2][128 * 32];
  __shared__ float Ms[KCH_A];
  __shared__ float Ls[KCH_A];
  const int tid = threadIdx.x, w = tid >> 6, lane = tid & 63;
  const int wr = w >> 1, wc = w & 1, quad = lane >> 4, l16 = lane & 15;
  const _Float16* Sb = S + (size_t)b * T_DIM * T_DIM;
  const _Float16* Vb = VT + (size_t)b * D_DIM * T_DIM;
  // inline column stats: thread tid owns column s = Kstart + tid
  {
    const int s = Kstart + tid;
    const int c0 = s >> 6;
    float m = -__builtin_inff(), l = 0.f;
    for (int base = c0 & ~7; base < NCH2; base += 8) {
      float pm[8], pl[8];
#pragma unroll
      for (int k = 0; k < 8; ++k) {
        size_t pidx = ((size_t)(base + k) * NB + b) * T_DIM + s;
        pm[k] = Pm[pidx];
        pl[k] = Pl[pidx];
      }
#pragma unroll
      for (int k = 0; k < 8; ++k)
        if (base + k >= c0) merge_stat(m, l, pm[k], pl[k]);
    }
    Ms[tid] = m;
    Ls[tid] = 1.f / l;
  }
  __syncthreads();  // Ms/Ls visible before prologue exp
  const int srow = lane >> 2;
  const int arow = tid >> 2, aseg = tid & 3;
  const int asw = (aseg ^ ((arow >> 1) & 3)) * 8;  // swizzled As dest seg
  f16x8 sv0, sv1;
  auto loadS = [&](int k0) {
    sv0 = *(const f16x8*)(Sb + (size_t)(t0 + arow) * T_DIM + k0 + aseg * 8);
    sv1 = *(const f16x8*)(Sb + (size_t)(t0 + 64 + arow) * T_DIM + k0 + aseg * 8);
  };
  auto stageB = [&](int buf, int k0) {
#pragma unroll
    for (int q = 0; q < 2; ++q) {
      int rbase = w * 32 + q * 16;
      int row = rbase + srow;
      int g = ((lane & 3) ^ ((row >> 1) & 3)) * 8;  // pre-swizzled source col
      gll16(Vb + (size_t)row * T_DIM + k0 + g, Bs[buf] + rbase * 32);
    }
  };
  auto writeA = [&](int buf, int k0) {
#pragma unroll
    for (int q = 0; q < 2; ++q) {
      f16x8 v = q ? sv1 : sv0;
      f16x8 o;
#pragma unroll
      for (int e = 0; e < 8; ++e) {
        int li = k0 + aseg * 8 + e - Kstart;
        o[e] = (_Float16)(__expf((float)v[e] - Ms[li]) * Ls[li]);
      }
      *(f16x8*)(As[buf] + (q * 64 + arow) * 32 + asw) = o;
    }
  };
  f32x4 acc[4][4] = {};
  loadS(Kstart);
  stageB(0, Kstart);
  asm volatile("s_waitcnt vmcnt(0)" ::: "memory");
  writeA(0, Kstart);
  for (int it = 0; it < nit; ++it) {
    const int cur = it & 1;
    const int k0 = Kstart + it * 32;
    __syncthreads();  // As/Bs[cur] complete
    if (it + 1 < nit) {
      loadS(k0 + 32);
      stageB(cur ^ 1, k0 + 32);
    }
    f16x8 af[4], bf[4];
#pragma unroll
    for (int i = 0; i < 4; ++i) {
      int row = wr * 64 + i * 16 + l16;
      int sg = (quad ^ ((row >> 1) & 3)) * 8;
      af[i] = *(const f16x8*)(As[cur] + row * 32 + sg);
    }
#pragma unroll
    for (int j = 0; j < 4; ++j) {
      int row = wc * 64 + j * 16 + l16;
      int sg = (quad ^ ((row >> 1) & 3)) * 8;
      bf[j] = *(const f16x8*)(Bs[cur] + row * 32 + sg);
    }
    __builtin_amdgcn_s_setprio(1);
#pragma unroll
    for (int i = 0; i < 4; ++i)
#pragma unroll
      for (int j = 0; j < 4; ++j)
        acc[i][j] = __builtin_amdgcn_mfma_f32_16x16x32_f16(af[i], bf[j], acc[i][j], 0, 0, 0);
    __builtin_amdgcn_s_setprio(0);
    if (it + 1 < nit) {
      asm volatile("s_waitcnt vmcnt(0)" ::: "memory");  // S regs + V gll16 landed
      writeA(cur ^ 1, k0 + 32);
    }
  }
  float* Zb = Z + (size_t)b * T_DIM * D_DIM;
#pragma unroll
  for (int i = 0; i < 4; ++i)
#pragma unroll
    for (int j = 0; j < 4; ++j) {
      int n = wc * 64 + j * 16 + l16;
#pragma unroll
      for (int r = 0; r < 4; ++r) {
        int t = t0 + wr * 64 + i * 16 + quad * 4 + r;
        atomicAdd(&Zb[(size_t)t * D_DIM + n], acc[i][j][r]);
      }
    }
}

// ---------------- launch ----------------

extern "C" void kernel_launch(void* const* d_in, const int* in_sizes, int n_in,
                              void* d_out, int out_size, void* d_ws, size_t ws_size,
                              hipStream_t stream) {
  const float* x = (const float*)d_in[0];
  const float* Wq = (const float*)d_in[1];
  const float* Wk = (const float*)d_in[2];
  const float* Wv = (const float*)d_in[3];
  char* ws = (char*)d_ws;
  // workspace layout (~60.3 MB), aliasing:
  //  [0, 48MB): Ph during proj (24 slots x 2 MB); S (33.5 MB) aliases after reduce
  _Float16* Ph = (_Float16*)(ws);                          // 50,331,648 B
  _Float16* S = (_Float16*)(ws);                           // 33,554,432 B (alias Ph)
  _Float16* WhT = (_Float16*)(ws + 50331648);              //  1,572,864 B
  _Float16* Qh = (_Float16*)(ws + 51904512);               //  2,097,152 B
  _Float16* Kh = (_Float16*)(ws + 54001664);               //  2,097,152 B
  _Float16* VT = (_Float16*)(ws + 56098816);               //  2,097,152 B
  float* Pm = (float*)(ws + 58195968);                     //  1,048,576 B
  float* Pl = (float*)(ws + 59244544);                     //  1,048,576 B
  float* Z = (float*)d_out;

  prep<<<dim3(1024, 4), 256, 0, stream>>>(Wq, Wk, Wv, WhT, Z);
  proj_gemm<<<dim3(128, KSP_P), 384, 0, stream>>>(x, WhT, Ph);
  proj_reduce<<<1536, 256, 0, stream>>>(Ph, Qh, Kh, VT);
  s_gemm<<<dim3(136, 4), 256, 0, stream>>>(Qh, Kh, S, Pm, Pl);
  av_gemm<<<dim3(16, 4, KSP_A), 256, 0, stream>>>(S, VT, Pm, Pl, Z);
}

// Round 5
// 165.981 us; speedup vs baseline: 2.0294x; 2.0294x over previous
//
#include <hip/hip_runtime.h>

typedef _Float16 f16x8 __attribute__((ext_vector_type(8)));
typedef _Float16 f16x4 __attribute__((ext_vector_type(4)));
typedef float f32x4 __attribute__((ext_vector_type(4)));

#define T_DIM 2048
#define E_DIM 2048
#define D_DIM 128
#define NB 4
#define KSP_P 4    // proj K-splits (K=2048 -> 512 each)
#define KCH_P 512
#define KSP_A 8    // av K-splits (chunks of 256 over s)
#define KCH_A 256
#define NCH2 32    // stats chunks of 64 t-rows

__device__ __forceinline__ void gll16(const void* g, void* l) {
  __builtin_amdgcn_global_load_lds(
      (const __attribute__((address_space(1))) unsigned int*)g,
      (__attribute__((address_space(3))) unsigned int*)l, 16, 0, 0);
}

__device__ __forceinline__ void merge_stat(float& m, float& l, float pm, float pl) {
  if (pm != -__builtin_inff()) {
    float nm = fmaxf(m, pm);
    l = l * __expf(m - nm) + pl * __expf(pm - nm);
    m = nm;
  }
}

// ---------------- W [E,D] fp32 -> WhT [D,E] fp16 (B^T layout), 3 matrices ----------------

__global__ void cvt_w(const float* __restrict__ Wq, const float* __restrict__ Wk,
                      const float* __restrict__ Wv, _Float16* __restrict__ WhT) {
  int idx = blockIdx.x * 256 + threadIdx.x;  // 0..262143
  int w = blockIdx.y;
  const float* W = (w == 0) ? Wq : ((w == 1) ? Wk : Wv);
  int e = idx & (E_DIM - 1), d = idx >> 11;
  WhT[(size_t)w * (D_DIM * E_DIM) + idx] = (_Float16)W[e * D_DIM + d];
}

// ---------------- projection GEMM: fused QKV, 128x384 tile, split-K x4, BK=32 ----------------
// EXACT r2 structure (best measured total, 166.5us): 12 waves (768 thr),
// wave = 64(M) x 64(N); wn>>1 selects matrix. A staged fp16 via reg-path,
// B via gll16 pre-swizzled. Double-buffered, ONE barrier per K-step.
// ONLY change vs r2: A16 now swizzled seg^((row>>1)&3) on write AND read.
// r2's linear [row][32] fp16 layout was an 8-way read conflict (64B row
// stride = 16 words mod 32 banks); swizzled is 2-way max (free, m136).
// Scheme validated by r3 (SQ_LDS_BANK_CONFLICT 1.57M -> 0, correct).

__global__ __launch_bounds__(768) void proj_gemm(
    const float* __restrict__ x, const _Float16* __restrict__ WhT,
    _Float16* __restrict__ Ph) {
  __shared__ _Float16 A16[2][128 * 32];  // 2 x 8 KB fp16, swizzled
  __shared__ _Float16 Bsw[2][384 * 32];  // 2 x 24 KB fp16, swizzled (Q|K|V rows)
  const int tid = threadIdx.x, w = tid >> 6, lane = tid & 63;
  const int wn = w >> 1, wr = w & 1, quad = lane >> 4, l16 = lane & 15;
  const int t0 = blockIdx.x * 128;
  const int ks = blockIdx.y;
  const int kb = ks * KCH_P;
  // A reg-staging: 512 threads, one row-seg each (row = tid>>2, seg = tid&3)
  const int arowA = tid >> 2, asegA = tid & 3;
  const int aswA = (asegA ^ ((arowA >> 1) & 3)) * 8;  // swizzled LDS dest seg
  // B staging: rows 0..191 (+192..383 second pass), seg pre-swizzled
  const int br = tid >> 2, bseg = tid & 3;

  f32x4 ax0, ax1;
  auto loadA = [&](int k0) {
    if (tid < 512) {
      const float* src = x + (size_t)(t0 + arowA) * E_DIM + k0 + asegA * 8;
      ax0 = *(const f32x4*)src;
      ax1 = *(const f32x4*)(src + 4);
    }
  };
  auto writeA = [&](int buf) {
    if (tid < 512) {
      f16x8 o;
#pragma unroll
      for (int e = 0; e < 4; ++e) {
        o[e] = (_Float16)ax0[e];
        o[e + 4] = (_Float16)ax1[e];
      }
      *(f16x8*)(&A16[buf][arowA * 32 + aswA]) = o;
    }
  };
  auto stageB = [&](int buf, int k0) {
    int g = bseg ^ ((br >> 1) & 3);
    gll16(WhT + (size_t)br * E_DIM + k0 + g * 8, &Bsw[buf][br * 32 + bseg * 8]);
    int r = 192 + br;
    int g2 = bseg ^ ((r >> 1) & 3);
    gll16(WhT + (size_t)r * E_DIM + k0 + g2 * 8, &Bsw[buf][r * 32 + bseg * 8]);
  };

  f32x4 acc[4][4] = {};
  loadA(kb);
  stageB(0, kb);
  asm volatile("s_waitcnt vmcnt(0)" ::: "memory");
  writeA(0);
  const int NIT = KCH_P / 32;  // 16
  for (int it = 0; it < NIT; ++it) {
    const int cur = it & 1;
    __syncthreads();  // buf[cur] complete (ds_writes + gll16 drained by barrier)
    if (it + 1 < NIT) {
      loadA(kb + (it + 1) * 32);
      stageB(cur ^ 1, kb + (it + 1) * 32);
    }
    f16x8 af[4], bf[4];
#pragma unroll
    for (int i = 0; i < 4; ++i) {
      int row = wr * 64 + i * 16 + l16;
      int sg = (quad ^ ((row >> 1) & 3)) * 8;
      af[i] = *(const f16x8*)(&A16[cur][row * 32 + sg]);
    }
#pragma unroll
    for (int j = 0; j < 4; ++j) {
      int row = wn * 64 + j * 16 + l16;
      int sg = (quad ^ ((row >> 1) & 3)) * 8;
      bf[j] = *(const f16x8*)(&Bsw[cur][row * 32 + sg]);
    }
    __builtin_amdgcn_s_setprio(1);
#pragma unroll
    for (int i = 0; i < 4; ++i)
#pragma unroll
      for (int j = 0; j < 4; ++j)
        acc[i][j] = __builtin_amdgcn_mfma_f32_16x16x32_f16(af[i], bf[j], acc[i][j], 0, 0, 0);
    __builtin_amdgcn_s_setprio(0);
    if (it + 1 < NIT) {
      asm volatile("s_waitcnt vmcnt(0)" ::: "memory");  // A regs + B gll16 landed
      writeA(cur ^ 1);
    }
  }
  const int mat = wn >> 1;
  const int nb0 = (wn & 1) * 64;
  _Float16* P = Ph + ((size_t)(ks * 3 + mat) << 20);
  if (mat < 2) {
#pragma unroll
    for (int i = 0; i < 4; ++i)
#pragma unroll
      for (int j = 0; j < 4; ++j) {
        int n = nb0 + j * 16 + l16;
#pragma unroll
        for (int r = 0; r < 4; ++r) {
          int t = t0 + wr * 64 + i * 16 + quad * 4 + r;
          P[(size_t)t * D_DIM + n] = (_Float16)acc[i][j][r];
        }
      }
  } else {
    // V: pre-transposed partial, 4 consecutive t at fixed n -> f16x4 store
#pragma unroll
    for (int i = 0; i < 4; ++i)
#pragma unroll
      for (int j = 0; j < 4; ++j) {
        int n = nb0 + j * 16 + l16;
        int t = t0 + wr * 64 + i * 16 + quad * 4;
        f16x4 o;
#pragma unroll
        for (int r = 0; r < 4; ++r) o[r] = (_Float16)acc[i][j][r];
        *(f16x4*)(P + ((size_t)(t >> 11) * D_DIM + n) * T_DIM + (t & (T_DIM - 1))) = o;
      }
  }
}

// ---------------- reduce proj partials (4 slots) -> Qh, Kh, VT ----------------

__global__ void proj_reduce(const _Float16* __restrict__ Ph, _Float16* __restrict__ Qh,
                            _Float16* __restrict__ Kh, _Float16* __restrict__ VT) {
  size_t u = ((size_t)blockIdx.x * 256 + threadIdx.x) * 8;
  int mat = (int)(u >> 20);
  size_t rem = u & ((1u << 20) - 1);
  float s[8] = {};
#pragma unroll
  for (int ks = 0; ks < KSP_P; ++ks) {
    f16x8 p = *(const f16x8*)(Ph + ((size_t)(ks * 3 + mat) << 20) + rem);
#pragma unroll
    for (int e = 0; e < 8; ++e) s[e] += (float)p[e];
  }
  f16x8 o;
#pragma unroll
  for (int e = 0; e < 8; ++e) o[e] = (_Float16)s[e];
  _Float16* dst = (mat == 0) ? Qh : ((mat == 1) ? Kh : VT);
  *(f16x8*)(dst + rem) = o;
}

// ---------------- S = Q K^T / sqrt(D), single-barrier full-K + fused stats ----------------
// grid (136, 4): triangular (t,s) tile pair, y = batch. B staged once (4 BK=32
// sub-tiles, swizzled); A direct global->VGPR; 64 MFMA straight; stats epilogue
// single-pass: masked/scaled values cached in regs.

__global__ __launch_bounds__(256) void s_gemm(const _Float16* __restrict__ Qh,
                                              const _Float16* __restrict__ Kh,
                                              _Float16* __restrict__ S,
                                              float* __restrict__ Pm,
                                              float* __restrict__ Pl) {
  // triangular decode
  int idx = blockIdx.x;
  int xt = (int)((sqrtf(8.f * idx + 1.f) - 1.f) * 0.5f);
  while ((xt + 1) * (xt + 2) / 2 <= idx) ++xt;
  while (xt * (xt + 1) / 2 > idx) --xt;
  int yt = idx - xt * (xt + 1) / 2;
  __shared__ _Float16 Bs[4][128 * 32];
  const int tid = threadIdx.x, w = tid >> 6, lane = tid & 63;
  const int wr = w >> 1, wc = w & 1, quad = lane >> 4, l16 = lane & 15;
  const int t0 = xt * 128, s0 = yt * 128, b = blockIdx.y;
  const _Float16* A = Qh + (size_t)b * T_DIM * D_DIM;
  const _Float16* B = Kh + (size_t)b * T_DIM * D_DIM;
  const int srow = lane >> 2;
  const int swz = ((lane & 3) ^ ((srow >> 1) & 3)) * 8;  // source-col swizzle
#pragma unroll
  for (int kq = 0; kq < 4; ++kq)
#pragma unroll
    for (int q = 0; q < 2; ++q) {
      int rbase = w * 32 + q * 16;
      gll16(B + (size_t)(s0 + rbase + srow) * D_DIM + kq * 32 + swz,
            Bs[kq] + rbase * 32);
    }
  __syncthreads();
  f32x4 acc[4][4] = {};
  const int bsg = (quad ^ ((l16 >> 1) & 3)) * 8;
#pragma unroll
  for (int kq = 0; kq < 4; ++kq) {
    f16x8 af[4], bf[4];
#pragma unroll
    for (int i = 0; i < 4; ++i)
      af[i] = *(const f16x8*)(A + (size_t)(t0 + wr * 64 + i * 16 + l16) * D_DIM +
                              kq * 32 + quad * 8);
#pragma unroll
    for (int j = 0; j < 4; ++j)
      bf[j] = *(const f16x8*)(Bs[kq] + (wc * 64 + j * 16 + l16) * 32 + bsg);
#pragma unroll
    for (int i = 0; i < 4; ++i)
#pragma unroll
      for (int j = 0; j < 4; ++j)
        acc[i][j] = __builtin_amdgcn_mfma_f32_16x16x32_f16(af[i], bf[j], acc[i][j], 0, 0, 0);
  }
  _Float16* Sb = S + (size_t)b * T_DIM * T_DIM;
  const float scale = 0.08838834764831845f;  // 1/sqrt(128)
  const float NEG = -__builtin_inff();
#pragma unroll
  for (int j = 0; j < 4; ++j) {
    const int s = s0 + wc * 64 + j * 16 + l16;
    float vv[16];
    float m = NEG;
#pragma unroll
    for (int i = 0; i < 4; ++i)
#pragma unroll
      for (int r = 0; r < 4; ++r) {
        int t = t0 + wr * 64 + i * 16 + quad * 4 + r;
        float v = (s > t) ? NEG : acc[i][j][r] * scale;
        Sb[(size_t)t * T_DIM + s] = (_Float16)v;
        vv[i * 4 + r] = v;
        m = fmaxf(m, v);
      }
    float l = 0.f;
    if (m != NEG) {
#pragma unroll
      for (int k = 0; k < 16; ++k) l += __expf(vv[k] - m);  // exp(-inf - m) = 0
    }
    // merge across quad dim (lanes xor 16, 32)
#pragma unroll
    for (int d = 16; d <= 32; d <<= 1) {
      float pm = __shfl_xor(m, d, 64);
      float pl = __shfl_xor(l, d, 64);
      merge_stat(m, l, pm, pl);
    }
    if (quad == 0) {
      int c = 2 * xt + wr;
      Pm[((size_t)c * NB + b) * T_DIM + s] = m;
      Pl[((size_t)c * NB + b) * T_DIM + s] = l;
    }
  }
}

// ---------------- combine partials, two-level: 32 chunks of 64 rows ----------------

__global__ __launch_bounds__(256) void comb_stats(const float* __restrict__ Pm,
                                                  const float* __restrict__ Pl,
                                                  float* __restrict__ M,
                                                  float* __restrict__ L) {
  __shared__ float sM[8][32];
  __shared__ float sL[8][32];
  const int g = threadIdx.x >> 5, sl = threadIdx.x & 31;
  const int c = blockIdx.x * 32 + sl;
  const int b = c >> 11, s = c & (T_DIM - 1);
  float m = -__builtin_inff(), l = 0.f;
#pragma unroll
  for (int k = 0; k < NCH2 / 8; ++k) {
    int ch = g * (NCH2 / 8) + k;
    if (ch >= (s >> 6)) {  // chunk intersects valid region (and is written)
      size_t idx = ((size_t)ch * NB + b) * T_DIM + s;
      merge_stat(m, l, Pm[idx], Pl[idx]);
    }
  }
  sM[g][sl] = m;
  sL[g][sl] = l;
  __syncthreads();
  if (threadIdx.x < 32) {
    const int c2 = blockIdx.x * 32 + threadIdx.x;
    float fm = -__builtin_inff(), fl = 0.f;
#pragma unroll
    for (int gg = 0; gg < 8; ++gg) merge_stat(fm, fl, sM[gg][threadIdx.x], sL[gg][threadIdx.x]);
    M[c2] = fm;
    L[c2] = 1.f / fl;
  }
}

// ---------------- Z = A V, split-K: grid (16, 4, KSP_A) ----------------
// EXACT r2 structure (dbuf, one barrier per K-step, T14 async split, Zp
// partials + z_reduce). ONLY change: As/Bs swizzled seg^((row>>1)&3)
// (linear layout was an 8-way read conflict since r0). As: swizzle on
// ds_write dest + read. Bs: pre-swizzled gll16 SOURCE col + swizzled read
// (both-sides-or-neither rule, m104/m231).

__global__ __launch_bounds__(256) void av_gemm(const _Float16* __restrict__ S,
                                               const _Float16* __restrict__ VT,
                                               const float* __restrict__ M,
                                               const float* __restrict__ L,
                                               float* __restrict__ Zp) {
  const int t0 = blockIdx.x * 128, b = blockIdx.y, ks = blockIdx.z;
  const int Kmax = t0 + 128;
  const int Kstart = ks * KCH_A;
  if (Kstart >= Kmax) return;
  const int Kend = (Kstart + KCH_A < Kmax) ? (Kstart + KCH_A) : Kmax;
  const int nit = (Kend - Kstart) >> 5;  // 4 or 8
  __shared__ _Float16 As[2][128 * 32];
  __shared__ _Float16 Bs[2][128 * 32];
  __shared__ float Ms[KCH_A];
  __shared__ float Ls[KCH_A];
  const int tid = threadIdx.x, w = tid >> 6, lane = tid & 63;
  const int wr = w >> 1, wc = w & 1, quad = lane >> 4, l16 = lane & 15;
  const _Float16* Sb = S + (size_t)b * T_DIM * T_DIM;
  const _Float16* Vb = VT + (size_t)b * D_DIM * T_DIM;
  for (int i = tid; i < Kend - Kstart; i += 256) {
    Ms[i] = M[b * T_DIM + Kstart + i];
    Ls[i] = L[b * T_DIM + Kstart + i];
  }
  const int srow = lane >> 2;
  const int arow = tid >> 2, aseg = tid & 3;
  const int asw = (aseg ^ ((arow >> 1) & 3)) * 8;  // swizzled As dest seg
  f16x8 sv0, sv1;
  auto loadS = [&](int k0) {
    sv0 = *(const f16x8*)(Sb + (size_t)(t0 + arow) * T_DIM + k0 + aseg * 8);
    sv1 = *(const f16x8*)(Sb + (size_t)(t0 + 64 + arow) * T_DIM + k0 + aseg * 8);
  };
  auto stageB = [&](int buf, int k0) {
#pragma unroll
    for (int q = 0; q < 2; ++q) {
      int rbase = w * 32 + q * 16;
      int row = rbase + srow;
      int g = ((lane & 3) ^ ((row >> 1) & 3)) * 8;  // pre-swizzled source col
      gll16(Vb + (size_t)row * T_DIM + k0 + g, Bs[buf] + rbase * 32);
    }
  };
  auto writeA = [&](int buf, int k0) {
#pragma unroll
    for (int q = 0; q < 2; ++q) {
      f16x8 v = q ? sv1 : sv0;
      f16x8 o;
#pragma unroll
      for (int e = 0; e < 8; ++e) {
        int li = k0 + aseg * 8 + e - Kstart;
        o[e] = (_Float16)(__expf((float)v[e] - Ms[li]) * Ls[li]);
      }
      *(f16x8*)(As[buf] + (q * 64 + arow) * 32 + asw) = o;
    }
  };
  f32x4 acc[4][4] = {};
  __syncthreads();  // Ms/Ls visible before prologue exp
  loadS(Kstart);
  stageB(0, Kstart);
  asm volatile("s_waitcnt vmcnt(0)" ::: "memory");
  writeA(0, Kstart);
  for (int it = 0; it < nit; ++it) {
    const int cur = it & 1;
    const int k0 = Kstart + it * 32;
    __syncthreads();  // As/Bs[cur] complete
    if (it + 1 < nit) {
      loadS(k0 + 32);
      stageB(cur ^ 1, k0 + 32);
    }
    f16x8 af[4], bf[4];
#pragma unroll
    for (int i = 0; i < 4; ++i) {
      int row = wr * 64 + i * 16 + l16;
      int sg = (quad ^ ((row >> 1) & 3)) * 8;
      af[i] = *(const f16x8*)(As[cur] + row * 32 + sg);
    }
#pragma unroll
    for (int j = 0; j < 4; ++j) {
      int row = wc * 64 + j * 16 + l16;
      int sg = (quad ^ ((row >> 1) & 3)) * 8;
      bf[j] = *(const f16x8*)(Bs[cur] + row * 32 + sg);
    }
    __builtin_amdgcn_s_setprio(1);
#pragma unroll
    for (int i = 0; i < 4; ++i)
#pragma unroll
      for (int j = 0; j < 4; ++j)
        acc[i][j] = __builtin_amdgcn_mfma_f32_16x16x32_f16(af[i], bf[j], acc[i][j], 0, 0, 0);
    __builtin_amdgcn_s_setprio(0);
    if (it + 1 < nit) {
      asm volatile("s_waitcnt vmcnt(0)" ::: "memory");  // S regs + V gll16 landed
      writeA(cur ^ 1, k0 + 32);
    }
  }
  float* Zb = Zp + ((size_t)ks * NB + b) * T_DIM * D_DIM;
#pragma unroll
  for (int i = 0; i < 4; ++i)
#pragma unroll
    for (int j = 0; j < 4; ++j) {
      int n = wc * 64 + j * 16 + l16;
#pragma unroll
      for (int r = 0; r < 4; ++r) {
        int t = t0 + wr * 64 + i * 16 + quad * 4 + r;
        Zb[(size_t)t * D_DIM + n] = acc[i][j][r];
      }
    }
}

// ---------------- reduce Z partials -> output ----------------

__global__ void z_reduce(const float* __restrict__ Zp, float* __restrict__ Z) {
  size_t flat = ((size_t)blockIdx.x * 256 + threadIdx.x) * 4;
  int t = (int)((flat >> 7) & (T_DIM - 1));
  int ns = ((t >> 7) + 2) >> 1;  // ceil((x+1)/2), x = t/128
  f32x4 s = {};
  for (int ks = 0; ks < ns; ++ks) {
    f32x4 p = *(const f32x4*)(Zp + ((size_t)ks * NB * T_DIM * D_DIM) + flat);
    s += p;
  }
  *(f32x4*)(Z + flat) = s;
}

// ---------------- launch ----------------

extern "C" void kernel_launch(void* const* d_in, const int* in_sizes, int n_in,
                              void* d_out, int out_size, void* d_ws, size_t ws_size,
                              hipStream_t stream) {
  const float* x = (const float*)d_in[0];
  const float* Wq = (const float*)d_in[1];
  const float* Wk = (const float*)d_in[2];
  const float* Wv = (const float*)d_in[3];
  char* ws = (char*)d_ws;
  // workspace layout (~79 MB), aliasing:
  //  [0, 33.5MB): Zp (av partials; region idle during proj/s phases)
  //  [41.4MB, 74.9MB): Ph during proj; overwritten by S after proj_reduce
  float* Zp = (float*)(ws);                                // 33,554,432 B
  _Float16* WhT = (_Float16*)(ws + 33554432);              //  1,572,864 B
  _Float16* Qh = (_Float16*)(ws + 35127296);               //  2,097,152 B
  _Float16* Kh = (_Float16*)(ws + 37224448);               //  2,097,152 B
  _Float16* VT = (_Float16*)(ws + 39321600);               //  2,097,152 B
  _Float16* S = (_Float16*)(ws + 41418752);                // 33,554,432 B
  _Float16* Ph = (_Float16*)(ws + 41418752);               // 25,165,824 B (alias S)
  float* M = (float*)(ws + 74973184);                      //     32,768 B
  float* L = (float*)(ws + 75005952);                      //     32,768 B
  float* Pm = (float*)(ws + 75038720);                     //  1,048,576 B
  float* Pl = (float*)(ws + 76087296);                     //  1,048,576 B
  float* Z = (float*)d_out;

  cvt_w<<<dim3(1024, 3), 256, 0, stream>>>(Wq, Wk, Wv, WhT);
  proj_gemm<<<dim3(64, KSP_P), 768, 0, stream>>>(x, WhT, Ph);
  proj_reduce<<<1536, 256, 0, stream>>>(Ph, Qh, Kh, VT);
  s_gemm<<<dim3(136, 4), 256, 0, stream>>>(Qh, Kh, S, Pm, Pl);
  comb_stats<<<256, 256, 0, stream>>>(Pm, Pl, M, L);
  av_gemm<<<dim3(16, 4, KSP_A), 256, 0, stream>>>(S, VT, M, L, Zp);
  z_reduce<<<1024, 256, 0, stream>>>(Zp, Z);
}